// Round 1
// baseline (1351.473 us; speedup 1.0000x reference)
//
#include <hip/hip_runtime.h>
#include <hip/hip_bf16.h>
#include <math.h>

// ---------------- problem constants ----------------
constexpr int NA  = 3200;     // atoms
constexpr int NE  = 51200;    // edges
constexpr int C   = 128;      // channels
constexpr int NK  = 123;      // k-points with |k| <= 0.6
constexpr int NKP = 128;      // padded stride for cosd/sind
constexpr int BG  = 8;        // graphs
constexpr float SKIPF = 0.57735026918962576f;  // 3^-0.5
constexpr float AVGN  = 16.0f;

__device__ __forceinline__ float dsilu(float x) { return x / (1.0f + expf(-x)); }

// ---------------- generic tiled f32 GEMM ----------------
// out[m,n] = scale * ( act(X@W + bias) + res1 + res2 )
// M % 64 == 0, N % 64 == 0, K in {8,64,128}. X:(M,K) W:(K,N) row-major.
template <int K, int ACT>
__global__ __launch_bounds__(256) void gemm_kernel(
    const float* __restrict__ X, const float* __restrict__ W,
    const float* __restrict__ bias, const float* __restrict__ res1,
    const float* __restrict__ res2, float* __restrict__ out,
    int M, int N, float scale)
{
    constexpr int K4 = K / 4;
    __shared__ float As[64 * K];
    __shared__ float Bs[K * 64];
    const int tid = threadIdx.x;
    const int m0 = blockIdx.x * 64;
    const int n0 = blockIdx.y * 64;

    // stage A tile (64 x K)
    const float4* X4 = (const float4*)X;
    float4* As4 = (float4*)As;
    for (int idx = tid; idx < 64 * K4; idx += 256) {
        int r = idx / K4, k4 = idx - r * K4;
        As4[idx] = X4[(size_t)(m0 + r) * K4 + k4];
    }
    // stage B tile (K x 64)
    const float4* W4 = (const float4*)W;
    float4* Bs4 = (float4*)Bs;
    const int N4 = N >> 2;
    for (int idx = tid; idx < K * 16; idx += 256) {
        int kr = idx >> 4, c4 = idx & 15;
        Bs4[idx] = W4[(size_t)kr * N4 + (n0 >> 2) + c4];
    }
    __syncthreads();

    const int tx = tid & 15;        // 4-col group
    const int ty = tid >> 4;        // 4-row group
    float acc[4][4];
#pragma unroll
    for (int i = 0; i < 4; i++)
#pragma unroll
        for (int j = 0; j < 4; j++) acc[i][j] = 0.0f;

    for (int k4 = 0; k4 < K4; k4++) {
        float a[4][4];
#pragma unroll
        for (int i = 0; i < 4; i++) {
            float4 av = As4[(ty * 4 + i) * K4 + k4];
            a[i][0] = av.x; a[i][1] = av.y; a[i][2] = av.z; a[i][3] = av.w;
        }
#pragma unroll
        for (int kk = 0; kk < 4; kk++) {
            float4 bv = Bs4[(k4 * 4 + kk) * 16 + tx];
#pragma unroll
            for (int i = 0; i < 4; i++) {
                acc[i][0] += a[i][kk] * bv.x;
                acc[i][1] += a[i][kk] * bv.y;
                acc[i][2] += a[i][kk] * bv.z;
                acc[i][3] += a[i][kk] * bv.w;
            }
        }
    }

    float4 bv = make_float4(0.f, 0.f, 0.f, 0.f);
    if (bias) bv = ((const float4*)bias)[(n0 >> 2) + tx];
#pragma unroll
    for (int i = 0; i < 4; i++) {
        int row = m0 + ty * 4 + i;
        size_t o = (size_t)row * N + n0 + tx * 4;
        float4 v;
        v.x = acc[i][0] + bv.x; v.y = acc[i][1] + bv.y;
        v.z = acc[i][2] + bv.z; v.w = acc[i][3] + bv.w;
        if (ACT) { v.x = dsilu(v.x); v.y = dsilu(v.y); v.z = dsilu(v.z); v.w = dsilu(v.w); }
        if (res1) { float4 r = *(const float4*)(res1 + o); v.x += r.x; v.y += r.y; v.z += r.z; v.w += r.w; }
        if (res2) { float4 r = *(const float4*)(res2 + o); v.x += r.x; v.y += r.y; v.z += r.z; v.w += r.w; }
        v.x *= scale; v.y *= scale; v.z *= scale; v.w *= scale;
        *(float4*)(out + o) = v;
    }
}

// ---------------- setup kernels ----------------
__global__ __launch_bounds__(128) void k_node_init(
    const float* __restrict__ na, const float* __restrict__ Wemb,
    const float* __restrict__ aE, const int* __restrict__ batch,
    float* __restrict__ h, float* __restrict__ Eout)
{
    int n = blockIdx.x, c = threadIdx.x;
    float s = 0.f;
#pragma unroll
    for (int k = 0; k < 10; k++) s += na[n * 10 + k] * Wemb[k * C + c];
    h[(size_t)n * C + c] = s;
    if (c == 0) {
        float e = 0.f;
#pragma unroll
        for (int k = 0; k < 10; k++) e += na[n * 10 + k] * aE[k];
        atomicAdd(&Eout[batch[n]], e);
    }
}

__global__ __launch_bounds__(256) void k_ranges(const int* __restrict__ batch, int* __restrict__ gs)
{
    __shared__ int cnt[BG];
    if (threadIdx.x < BG) cnt[threadIdx.x] = 0;
    __syncthreads();
    for (int n = threadIdx.x; n < NA; n += 256) atomicAdd(&cnt[batch[n]], 1);
    __syncthreads();
    if (threadIdx.x == 0) {
        int s = 0;
        for (int b = 0; b < BG; b++) { gs[b] = s; s += cnt[b]; }
        gs[BG] = s;
    }
}

__device__ __forceinline__ float sincn(float x) {
    float px = 3.14159265358979323846f * x;
    return (fabsf(px) < 1e-8f) ? 1.0f : (sinf(px) / px);
}

__global__ __launch_bounds__(128) void k_kspace(
    const float* __restrict__ pos, const float* __restrict__ kgrid,
    float* __restrict__ cosd, float* __restrict__ sind)
{
    int n = blockIdx.x, k = threadIdx.x;
    float p0 = pos[n * 3 + 0], p1 = pos[n * 3 + 1], p2 = pos[n * 3 + 2];
    float sd = sincn(0.1f * p0) * sincn(0.1f * p1) * sincn(0.1f * p2);
    if (k < NK) {
        float d = p0 * kgrid[k * 3 + 0] + p1 * kgrid[k * 3 + 1] + p2 * kgrid[k * 3 + 2];
        float sn, cs;
        sincosf(d, &sn, &cs);
        cosd[(size_t)n * NKP + k] = sd * cs;
        sind[(size_t)n * NKP + k] = sd * sn;
    } else {
        cosd[(size_t)n * NKP + k] = 0.f;
        sind[(size_t)n * NKP + k] = 0.f;
    }
}

__global__ __launch_bounds__(1024) void k_kdown(
    const float* __restrict__ krbf, const float* __restrict__ Wdown, float* __restrict__ kdown)
{
    int t = threadIdx.x;
    if (t < NK * 8) {
        int k = t >> 3, j = t & 7;
        float s = 0.f;
        for (int r = 0; r < 128; r++) s += krbf[k * 128 + r] * Wdown[r * 8 + j];
        kdown[t] = s;
    }
}

__global__ __launch_bounds__(256) void k_edge_geom(
    const float* __restrict__ pos, const float* __restrict__ shifts,
    const int* __restrict__ eidx, float* __restrict__ Y, float* __restrict__ ef)
{
    int e = blockIdx.x * 256 + threadIdx.x;
    if (e >= NE) return;
    int s = eidx[e], d = eidx[NE + e];
    float vx = pos[d * 3 + 0] - pos[s * 3 + 0] + shifts[e * 3 + 0];
    float vy = pos[d * 3 + 1] - pos[s * 3 + 1] + shifts[e * 3 + 1];
    float vz = pos[d * 3 + 2] - pos[s * 3 + 2] + shifts[e * 3 + 2];
    float r = sqrtf(vx * vx + vy * vy + vz * vz);
    float rinv = 1.0f / fmaxf(r, 1e-9f);
    float x = vx * rinv, y = vy * rinv, z = vz * rinv;

    const float s3 = 1.7320508075688772f, s5 = 2.2360679774997896f, s15 = 3.8729833462074170f;
    const float c70 = 2.0916500663351889f;   // sqrt(70)/4
    const float c105 = 10.246950765959598f;  // sqrt(105)
    const float c42 = 1.6201851746019651f;   // sqrt(42)/4
    const float c7 = 1.3228756555322954f;    // sqrt(7)/2
    float o[16];
    o[0] = 1.0f;
    o[1] = s3 * x; o[2] = s3 * y; o[3] = s3 * z;
    o[4] = s15 * x * y; o[5] = s15 * y * z; o[6] = 0.5f * s5 * (3.f * z * z - 1.f);
    o[7] = s15 * x * z; o[8] = 0.5f * s15 * (x * x - y * y);
    o[9]  = c70 * y * (3.f * x * x - y * y);
    o[10] = c105 * x * y * z;
    o[11] = c42 * y * (5.f * z * z - 1.f);
    o[12] = c7 * z * (5.f * z * z - 3.f);
    o[13] = c42 * x * (5.f * z * z - 1.f);
    o[14] = 0.5f * c105 * z * (x * x - y * y);
    o[15] = c70 * x * (x * x - 3.f * y * y);
    float4* Y4 = (float4*)(Y + (size_t)e * 16);
    Y4[0] = make_float4(o[0], o[1], o[2], o[3]);
    Y4[1] = make_float4(o[4], o[5], o[6], o[7]);
    Y4[2] = make_float4(o[8], o[9], o[10], o[11]);
    Y4[3] = make_float4(o[12], o[13], o[14], o[15]);

    float uu = fminf(fmaxf(r * 0.2f, 0.f), 1.f);
    float u2 = uu * uu, u4 = u2 * u2, u5 = u4 * uu, u6 = u5 * uu, u7 = u6 * uu;
    float env = 1.f - 21.f * u5 + 35.f * u6 - 15.f * u7;
    env = (r < 5.0f) ? env : 0.0f;
    float pref = 0.63245553203367587f * rinv * env;  // sqrt(2/5)/r * env
    const float pio5 = 0.62831853071795865f;         // pi/5
    float efv[8];
#pragma unroll
    for (int n1 = 1; n1 <= 8; n1++) efv[n1 - 1] = pref * sinf(n1 * pio5 * r);
    float4* E4 = (float4*)(ef + (size_t)e * 8);
    E4[0] = make_float4(efv[0], efv[1], efv[2], efv[3]);
    E4[1] = make_float4(efv[4], efv[5], efv[6], efv[7]);
}

// ---------------- CSR by dst ----------------
__global__ __launch_bounds__(256) void k_count(const int* __restrict__ eidx, int* __restrict__ deg)
{
    int e = blockIdx.x * 256 + threadIdx.x;
    if (e < NE) atomicAdd(&deg[eidx[NE + e]], 1);
}

__global__ __launch_bounds__(1024) void k_scan(
    const int* __restrict__ deg, int* __restrict__ offs, int* __restrict__ cursor)
{
    __shared__ int sc[1024];
    int tid = threadIdx.x;
    int base = tid * 4;
    int v[4]; int s = 0;
#pragma unroll
    for (int i = 0; i < 4; i++) {
        int idx = base + i;
        int d = (idx < NA) ? deg[idx] : 0;
        v[i] = s; s += d;
    }
    sc[tid] = s;
    __syncthreads();
    for (int ofs = 1; ofs < 1024; ofs <<= 1) {
        int t = (tid >= ofs) ? sc[tid - ofs] : 0;
        __syncthreads();
        sc[tid] += t;
        __syncthreads();
    }
    int excl = (tid > 0) ? sc[tid - 1] : 0;
#pragma unroll
    for (int i = 0; i < 4; i++) {
        int idx = base + i;
        if (idx < NA) { int o = excl + v[i]; offs[idx] = o; cursor[idx] = o; }
    }
    if (tid == 1023) offs[NA] = sc[1023];
}

__global__ __launch_bounds__(256) void k_fill(
    const int* __restrict__ eidx, int* __restrict__ cursor, int* __restrict__ perm)
{
    int e = blockIdx.x * 256 + threadIdx.x;
    if (e < NE) {
        int d = eidx[NE + e];
        int p = atomicAdd(&cursor[d], 1);
        perm[p] = e;
    }
}

// ---------------- Ewald kernels ----------------
__global__ __launch_bounds__(128) void k_kfilter(
    const float* __restrict__ kdown, const float* __restrict__ WupE, float* __restrict__ kf)
{
    int k = blockIdx.x, c = threadIdx.x;
    float s = 0.f;
#pragma unroll
    for (int j = 0; j < 8; j++) s += kdown[k * 8 + j] * WupE[j * C + c];
    kf[(size_t)k * C + c] = s;
}

__global__ __launch_bounds__(128) void k_sf(
    const float* __restrict__ hres, const float* __restrict__ cosd, const float* __restrict__ sind,
    const int* __restrict__ gs, float* __restrict__ sfr, float* __restrict__ sfi)
{
    int bk = blockIdx.x;
    int b = bk / NK, k = bk - b * NK;
    int c = threadIdx.x;
    int n0 = gs[b], n1 = gs[b + 1];
    float ar = 0.f, ai = 0.f;
    for (int n = n0; n < n1; n++) {
        float hc = hres[(size_t)n * C + c];
        float cd = cosd[(size_t)n * NKP + k];
        float sd = sind[(size_t)n * NKP + k];
        ar += hc * cd;
        ai += hc * sd;
    }
    sfr[(size_t)bk * C + c] = ar;
    sfi[(size_t)bk * C + c] = ai;
}

__global__ __launch_bounds__(128) void k_sfk(
    float* __restrict__ sfr, float* __restrict__ sfi, const float* __restrict__ kf)
{
    int bk = blockIdx.x;
    int k = bk % NK;
    int c = threadIdx.x;
    float v = kf[(size_t)k * C + c] * 0.01f;
    sfr[(size_t)bk * C + c] *= v;
    sfi[(size_t)bk * C + c] *= v;
}

__global__ __launch_bounds__(128) void k_he(
    const float* __restrict__ cosd, const float* __restrict__ sind,
    const float* __restrict__ sfr, const float* __restrict__ sfi,
    const int* __restrict__ batch, float* __restrict__ out)
{
    int n = blockIdx.x, c = threadIdx.x;
    int b = batch[n];
    const float* pr = sfr + (size_t)b * NK * C;
    const float* pi = sfi + (size_t)b * NK * C;
    const float* cdp = cosd + (size_t)n * NKP;
    const float* sdp = sind + (size_t)n * NKP;
    float acc = 0.f;
    for (int k = 0; k < NK; k++) {
        acc += cdp[k] * pr[(size_t)k * C + c] + sdp[k] * pi[(size_t)k * C + c];
    }
    out[(size_t)n * C + c] = acc;
}

// ---------------- message gather + symmetric contraction ----------------
__global__ __launch_bounds__(128) void k_gather(
    const float* __restrict__ wbuf, const float* __restrict__ hu,
    const float* __restrict__ Y, const int* __restrict__ srcArr,
    const int* __restrict__ offs, const int* __restrict__ perm,
    const float* __restrict__ w2, const float* __restrict__ w3,
    float* __restrict__ feats)
{
    int n = blockIdx.x, c = threadIdx.x;
    int j0 = offs[n], j1 = offs[n + 1];
    float A[16];
#pragma unroll
    for (int s = 0; s < 16; s++) A[s] = 0.f;
    for (int j = j0; j < j1; j++) {
        int e = perm[j];
        int s = srcArr[e];
        float huc = hu[(size_t)s * C + c];
        float4 wv = *(const float4*)(wbuf + (size_t)e * 512 + c * 4);
        const float4* Yp = (const float4*)(Y + (size_t)e * 16);
        float4 y0 = Yp[0], y1 = Yp[1], y2 = Yp[2], y3 = Yp[3];
        float m0 = wv.x * huc, m1 = wv.y * huc, m2 = wv.z * huc, m3 = wv.w * huc;
        A[0] += m0 * y0.x;
        A[1] += m1 * y0.y;  A[2]  += m1 * y0.z;  A[3]  += m1 * y0.w;
        A[4] += m2 * y1.x;  A[5]  += m2 * y1.y;  A[6]  += m2 * y1.z;  A[7] += m2 * y1.w;
        A[8] += m2 * y2.x;
        A[9] += m3 * y2.y;  A[10] += m3 * y2.z;  A[11] += m3 * y2.w;
        A[12] += m3 * y3.x; A[13] += m3 * y3.y;  A[14] += m3 * y3.z;  A[15] += m3 * y3.w;
    }
    const float inv = 1.0f / AVGN;
#pragma unroll
    for (int s = 0; s < 16; s++) A[s] *= inv;
    float scal = A[0];
    float i0 = A[0] * A[0];
    float i1 = A[1] * A[1] + A[2] * A[2] + A[3] * A[3];
    float i2 = A[4] * A[4] + A[5] * A[5] + A[6] * A[6] + A[7] * A[7] + A[8] * A[8];
    float i3 = A[9] * A[9] + A[10] * A[10] + A[11] * A[11] + A[12] * A[12] +
               A[13] * A[13] + A[14] * A[14] + A[15] * A[15];
    float t2 = i0 * w2[c] + i1 * w2[C + c] + i2 * w2[2 * C + c] + i3 * w2[3 * C + c];
    float t3 = i0 * w3[c] + i1 * w3[C + c] + i2 * w3[2 * C + c] + i3 * w3[3 * C + c];
    feats[(size_t)n * C + c] = scal + t2 + scal * t3;
}

// ---------------- readout energy ----------------
__global__ __launch_bounds__(128) void k_node_energy(
    const float* __restrict__ h, const int* __restrict__ batch,
    const float* __restrict__ Wr0, const float* __restrict__ Wr1a,
    const float* __restrict__ Wr1b, int mode, float* __restrict__ Eout)
{
    int n = blockIdx.x, t = threadIdx.x;
    __shared__ float hs[128];
    __shared__ float red[16];
    float hv = h[(size_t)n * C + t];
    if (mode == 0) {
        float v = hv * Wr0[t];
#pragma unroll
        for (int o = 32; o; o >>= 1) v += __shfl_down(v, o, 64);
        if ((t & 63) == 0) red[t >> 6] = v;
        __syncthreads();
        if (t == 0) atomicAdd(&Eout[batch[n]], red[0] + red[1]);
    } else {
        hs[t] = hv;
        __syncthreads();
        if (t < 16) {
            float s = 0.f;
#pragma unroll 8
            for (int cc = 0; cc < 128; cc++) s += hs[cc] * Wr1a[cc * 16 + t];
            red[t] = dsilu(s) * Wr1b[t];
        }
        __syncthreads();
        if (t == 0) {
            float s = 0.f;
#pragma unroll
            for (int j = 0; j < 16; j++) s += red[j];
            atomicAdd(&Eout[batch[n]], s);
        }
    }
}

// ---------------- workspace layout (floats) ----------------
constexpr size_t NAC   = (size_t)NA * C;       // 409600
constexpr size_t F_COSD = 0;
constexpr size_t F_SIND = F_COSD + (size_t)NA * NKP;
constexpr size_t F_Y    = F_SIND + (size_t)NA * NKP;
constexpr size_t F_EF   = F_Y + (size_t)NE * 16;
constexpr size_t F_H    = F_EF + (size_t)NE * 8;
constexpr size_t F_HN   = F_H + NAC;
constexpr size_t F_HRES = F_HN + NAC;
constexpr size_t F_T1   = F_HRES + NAC;
constexpr size_t F_T2   = F_T1 + NAC;
constexpr size_t F_HE2  = F_T2 + NAC;
constexpr size_t F_HU   = F_HE2 + NAC;
constexpr size_t F_FE   = F_HU + NAC;
constexpr size_t F_TA   = F_FE + NAC;
constexpr size_t F_TB   = F_TA + (size_t)NE * 64;
constexpr size_t F_W    = F_TB + (size_t)NE * 64;
constexpr size_t F_SFR  = F_W + (size_t)NE * 512;
constexpr size_t F_SFI  = F_SFR + (size_t)BG * NK * C;
constexpr size_t F_KD   = F_SFI + (size_t)BG * NK * C;
constexpr size_t F_KF   = F_KD + 1024;
constexpr size_t F_END  = F_KF + (size_t)NK * C;
constexpr size_t I_BASE = ((F_END * 4 + 255) / 256) * 256;  // byte offset of int region

extern "C" void kernel_launch(void* const* d_in, const int* in_sizes, int n_in,
                              void* d_out, int out_size, void* d_ws, size_t ws_size,
                              hipStream_t stream) {
    const float* pos    = (const float*)d_in[0];
    const float* na     = (const float*)d_in[1];
    const float* shifts = (const float*)d_in[2];
    const int*   eidx   = (const int*)d_in[3];
    const int*   batch  = (const int*)d_in[4];
    const float* kgrid  = (const float*)d_in[5];
    const float* krbf   = (const float*)d_in[6];
    const float* Wemb   = (const float*)d_in[7];
    const float* aE     = (const float*)d_in[8];
    const float* rW1    = (const float*)d_in[9];
    const float* rb1    = (const float*)d_in[10];
    const float* rW2    = (const float*)d_in[11];
    const float* rb2    = (const float*)d_in[12];
    const float* rW3    = (const float*)d_in[13];
    const float* rb3    = (const float*)d_in[14];
    const float* rW4    = (const float*)d_in[15];
    const float* Wup    = (const float*)d_in[16];
    const float* w2     = (const float*)d_in[17];
    const float* w3     = (const float*)d_in[18];
    const float* Wmix   = (const float*)d_in[19];
    const float* Wr0    = (const float*)d_in[20];
    const float* Wr1a   = (const float*)d_in[21];
    const float* Wr1b   = (const float*)d_in[22];
    const float* Wdown  = (const float*)d_in[23];
    const float* WupE   = (const float*)d_in[24];
    const float* Wpre1  = (const float*)d_in[25];
    const float* bpre1  = (const float*)d_in[26];
    const float* Wpre2  = (const float*)d_in[27];
    const float* bpre2  = (const float*)d_in[28];
    const float* Wm1    = (const float*)d_in[29];
    const float* bm1    = (const float*)d_in[30];
    const float* Wm2    = (const float*)d_in[31];
    const float* bm2    = (const float*)d_in[32];

    float* fw = (float*)d_ws;
    float* cosd = fw + F_COSD;
    float* sind = fw + F_SIND;
    float* Ybuf = fw + F_Y;
    float* efb  = fw + F_EF;
    float* h    = fw + F_H;
    float* hn   = fw + F_HN;
    float* hres = fw + F_HRES;
    float* t1   = fw + F_T1;
    float* t2   = fw + F_T2;
    float* he2  = fw + F_HE2;
    float* hu   = fw + F_HU;
    float* fe   = fw + F_FE;
    float* tA   = fw + F_TA;
    float* tB   = fw + F_TB;
    float* wbuf = fw + F_W;
    float* sfr  = fw + F_SFR;
    float* sfi  = fw + F_SFI;
    float* kdwn = fw + F_KD;
    float* kfil = fw + F_KF;

    int* ip     = (int*)((char*)d_ws + I_BASE);
    int* deg    = ip;
    int* offs   = ip + NA;
    int* cursor = ip + 2 * NA + 1;
    int* perm   = ip + 3 * NA + 1;
    int* gs     = perm + NE;

    float* Eout = (float*)d_out;

    hipMemsetAsync(Eout, 0, BG * sizeof(float), stream);
    hipMemsetAsync(deg, 0, NA * sizeof(int), stream);

    k_node_init<<<NA, 128, 0, stream>>>(na, Wemb, aE, batch, h, Eout);
    k_ranges<<<1, 256, 0, stream>>>(batch, gs);
    k_kspace<<<NA, 128, 0, stream>>>(pos, kgrid, cosd, sind);
    k_kdown<<<1, 1024, 0, stream>>>(krbf, Wdown, kdwn);
    k_edge_geom<<<NE / 256, 256, 0, stream>>>(pos, shifts, eidx, Ybuf, efb);
    k_count<<<NE / 256, 256, 0, stream>>>(eidx, deg);
    k_scan<<<1, 1024, 0, stream>>>(deg, offs, cursor);
    k_fill<<<NE / 256, 256, 0, stream>>>(eidx, cursor, perm);

    const dim3 gA(NA / 64, C / 64);       // atom GEMMs: 50 x 2
    const dim3 gE1(NE / 64, 1);           // edge GEMMs N=64: 800 x 1
    const dim3 gE4(NE / 64, 512 / 64);    // edge GEMM N=512: 800 x 8

    for (int i = 0; i < 2; i++) {
        const float* Wpre1_i = Wpre1 + (size_t)i * C * C;
        const float* bpre1_i = bpre1 + (size_t)i * C;
        const float* Wpre2_i = Wpre2 + (size_t)i * C * C;
        const float* bpre2_i = bpre2 + (size_t)i * C;
        const float* WupE_i  = WupE + (size_t)i * 8 * C;
        const float* Wm1_i   = Wm1 + (size_t)i * C * C;
        const float* bm1_i   = bm1 + (size_t)i * C;
        const float* Wm2_i   = Wm2 + (size_t)i * C * C;
        const float* bm2_i   = bm2 + (size_t)i * C;
        const float* Wup_i   = Wup + (size_t)i * C * C;
        const float* rW1_i   = rW1 + (size_t)i * 8 * 64;
        const float* rb1_i   = rb1 + (size_t)i * 64;
        const float* rW2_i   = rW2 + (size_t)i * 64 * 64;
        const float* rb2_i   = rb2 + (size_t)i * 64;
        const float* rW3_i   = rW3 + (size_t)i * 64 * 64;
        const float* rb3_i   = rb3 + (size_t)i * 64;
        const float* rW4_i   = rW4 + (size_t)i * 64 * 512;
        const float* w2_i    = w2 + (size_t)i * 4 * C;
        const float* w3_i    = w3 + (size_t)i * 4 * C;
        const float* Wmix_i  = Wmix + (size_t)i * C * C;

        // Ewald branch
        gemm_kernel<128, 1><<<gA, 256, 0, stream>>>(h, Wpre1_i, bpre1_i, nullptr, nullptr, t1, NA, C, 1.f);
        gemm_kernel<128, 0><<<gA, 256, 0, stream>>>(t1, Wpre2_i, bpre2_i, h, nullptr, hres, NA, C, 1.f);
        k_kfilter<<<NK, 128, 0, stream>>>(kdwn, WupE_i, kfil);
        k_sf<<<BG * NK, 128, 0, stream>>>(hres, cosd, sind, gs, sfr, sfi);
        k_sfk<<<BG * NK, 128, 0, stream>>>(sfr, sfi, kfil);
        k_he<<<NA, 128, 0, stream>>>(cosd, sind, sfr, sfi, batch, t1);
        gemm_kernel<128, 1><<<gA, 256, 0, stream>>>(t1, Wm1_i, bm1_i, nullptr, nullptr, t2, NA, C, 1.f);
        gemm_kernel<128, 1><<<gA, 256, 0, stream>>>(t2, Wm2_i, bm2_i, nullptr, nullptr, he2, NA, C, 1.f);

        // message branch
        gemm_kernel<128, 0><<<gA, 256, 0, stream>>>(h, Wup_i, nullptr, nullptr, nullptr, hu, NA, C, 1.f);
        gemm_kernel<8, 1><<<gE1, 256, 0, stream>>>(efb, rW1_i, rb1_i, nullptr, nullptr, tA, NE, 64, 1.f);
        gemm_kernel<64, 1><<<gE1, 256, 0, stream>>>(tA, rW2_i, rb2_i, nullptr, nullptr, tB, NE, 64, 1.f);
        gemm_kernel<64, 1><<<gE1, 256, 0, stream>>>(tB, rW3_i, rb3_i, nullptr, nullptr, tA, NE, 64, 1.f);
        gemm_kernel<64, 0><<<gE4, 256, 0, stream>>>(tA, rW4_i, nullptr, nullptr, nullptr, wbuf, NE, 512, 1.f);
        k_gather<<<NA, 128, 0, stream>>>(wbuf, hu, Ybuf, eidx, offs, perm, w2_i, w3_i, fe);

        // combine: h_new = SKIP * (feats@Wmix + h + he2)
        gemm_kernel<128, 0><<<gA, 256, 0, stream>>>(fe, Wmix_i, nullptr, h, he2, hn, NA, C, SKIPF);
        k_node_energy<<<NA, 128, 0, stream>>>(hn, batch, Wr0, Wr1a, Wr1b, (i == 0) ? 0 : 1, Eout);

        float* tmp = h; h = hn; hn = tmp;
    }
}

// Round 2
// 902.385 us; speedup vs baseline: 1.4977x; 1.4977x over previous
//
#include <hip/hip_runtime.h>
#include <hip/hip_bf16.h>
#include <math.h>

// ---------------- problem constants ----------------
constexpr int NA  = 3200;     // atoms
constexpr int NE  = 51200;    // edges
constexpr int C   = 128;      // channels
constexpr int NK  = 123;      // k-points with |k| <= 0.6
constexpr int NKP = 128;      // padded stride for cosd/sind
constexpr int BG  = 8;        // graphs
constexpr float SKIPF = 0.57735026918962576f;  // 3^-0.5
constexpr float AVGN  = 16.0f;

__device__ __forceinline__ float dsilu(float x) { return x / (1.0f + expf(-x)); }

__device__ __forceinline__ unsigned short f2bf(float f) {
    unsigned int u = __float_as_uint(f);
    unsigned int r = (u + 0x7fffu + ((u >> 16) & 1u)) >> 16;
    return (unsigned short)r;
}
__device__ __forceinline__ float bf2f(unsigned short s) {
    return __uint_as_float(((unsigned int)s) << 16);
}

// ---------------- generic tiled f32 GEMM ----------------
// out[m,n] = scale * ( act(X@W + bias) + res1 + res2 )
// M % 64 == 0, N % 64 == 0. X:(M,K) W:(K,N) row-major.
// K-chunked at BK=64, A-tile padded (+1 float4/row) to kill bank conflicts.
// OBF16: store output as bf16 instead of f32.
template <int K, int ACT, int OBF16>
__global__ __launch_bounds__(256, 4) void gemm_kernel(
    const float* __restrict__ X, const float* __restrict__ W,
    const float* __restrict__ bias, const float* __restrict__ res1,
    const float* __restrict__ res2, void* __restrict__ outv,
    int M, int N, float scale)
{
    constexpr int K4 = K / 4;
    constexpr int BK  = (K < 64) ? K : 64;
    constexpr int BK4 = BK / 4;
    constexpr int BK4P = BK4 + 1;          // padded row stride (float4)
    __shared__ float As[64 * BK4P * 4];
    __shared__ float Bs[BK * 64];
    const int tid = threadIdx.x;
    const int m0 = blockIdx.x * 64;
    const int n0 = blockIdx.y * 64;

    const float4* X4 = (const float4*)X;
    const float4* W4 = (const float4*)W;
    float4* As4 = (float4*)As;
    float4* Bs4 = (float4*)Bs;
    const int N4 = N >> 2;

    const int tx = tid & 15;        // 4-col group
    const int ty = tid >> 4;        // 4-row group
    float acc[4][4];
#pragma unroll
    for (int i = 0; i < 4; i++)
#pragma unroll
        for (int j = 0; j < 4; j++) acc[i][j] = 0.0f;

    for (int k0 = 0; k0 < K4; k0 += BK4) {
        if (k0) __syncthreads();
        // stage A tile (64 x BK), padded rows
        for (int idx = tid; idx < 64 * BK4; idx += 256) {
            int r = idx / BK4, k4 = idx - r * BK4;
            As4[r * BK4P + k4] = X4[(size_t)(m0 + r) * K4 + k0 + k4];
        }
        // stage B tile (BK x 64)
        for (int idx = tid; idx < BK * 16; idx += 256) {
            int kr = idx >> 4, c4 = idx & 15;
            Bs4[idx] = W4[(size_t)(k0 * 4 + kr) * N4 + (n0 >> 2) + c4];
        }
        __syncthreads();

#pragma unroll 4
        for (int k4 = 0; k4 < BK4; k4++) {
            float a[4][4];
#pragma unroll
            for (int i = 0; i < 4; i++) {
                float4 av = As4[(ty * 4 + i) * BK4P + k4];
                a[i][0] = av.x; a[i][1] = av.y; a[i][2] = av.z; a[i][3] = av.w;
            }
#pragma unroll
            for (int kk = 0; kk < 4; kk++) {
                float4 bv = Bs4[(k4 * 4 + kk) * 16 + tx];
#pragma unroll
                for (int i = 0; i < 4; i++) {
                    acc[i][0] += a[i][kk] * bv.x;
                    acc[i][1] += a[i][kk] * bv.y;
                    acc[i][2] += a[i][kk] * bv.z;
                    acc[i][3] += a[i][kk] * bv.w;
                }
            }
        }
    }

    float4 bv = make_float4(0.f, 0.f, 0.f, 0.f);
    if (bias) bv = ((const float4*)bias)[(n0 >> 2) + tx];
#pragma unroll
    for (int i = 0; i < 4; i++) {
        int row = m0 + ty * 4 + i;
        size_t o = (size_t)row * N + n0 + tx * 4;
        float4 v;
        v.x = acc[i][0] + bv.x; v.y = acc[i][1] + bv.y;
        v.z = acc[i][2] + bv.z; v.w = acc[i][3] + bv.w;
        if (ACT) { v.x = dsilu(v.x); v.y = dsilu(v.y); v.z = dsilu(v.z); v.w = dsilu(v.w); }
        if (res1) { float4 r = *(const float4*)(res1 + o); v.x += r.x; v.y += r.y; v.z += r.z; v.w += r.w; }
        if (res2) { float4 r = *(const float4*)(res2 + o); v.x += r.x; v.y += r.y; v.z += r.z; v.w += r.w; }
        v.x *= scale; v.y *= scale; v.z *= scale; v.w *= scale;
        if (OBF16) {
            ushort4 pk;
            pk.x = f2bf(v.x); pk.y = f2bf(v.y); pk.z = f2bf(v.z); pk.w = f2bf(v.w);
            *(ushort4*)((unsigned short*)outv + o) = pk;
        } else {
            *(float4*)((float*)outv + o) = v;
        }
    }
}

// ---------------- setup kernels ----------------
__global__ __launch_bounds__(128) void k_node_init(
    const float* __restrict__ na, const float* __restrict__ Wemb,
    const float* __restrict__ aE, const int* __restrict__ batch,
    float* __restrict__ h, float* __restrict__ Eout)
{
    int n = blockIdx.x, c = threadIdx.x;
    float s = 0.f;
#pragma unroll
    for (int k = 0; k < 10; k++) s += na[n * 10 + k] * Wemb[k * C + c];
    h[(size_t)n * C + c] = s;
    if (c == 0) {
        float e = 0.f;
#pragma unroll
        for (int k = 0; k < 10; k++) e += na[n * 10 + k] * aE[k];
        atomicAdd(&Eout[batch[n]], e);
    }
}

__global__ __launch_bounds__(256) void k_ranges(const int* __restrict__ batch, int* __restrict__ gs)
{
    __shared__ int cnt[BG];
    if (threadIdx.x < BG) cnt[threadIdx.x] = 0;
    __syncthreads();
    for (int n = threadIdx.x; n < NA; n += 256) atomicAdd(&cnt[batch[n]], 1);
    __syncthreads();
    if (threadIdx.x == 0) {
        int s = 0;
        for (int b = 0; b < BG; b++) { gs[b] = s; s += cnt[b]; }
        gs[BG] = s;
    }
}

__device__ __forceinline__ float sincn(float x) {
    float px = 3.14159265358979323846f * x;
    return (fabsf(px) < 1e-8f) ? 1.0f : (sinf(px) / px);
}

__global__ __launch_bounds__(128) void k_kspace(
    const float* __restrict__ pos, const float* __restrict__ kgrid,
    float* __restrict__ cosd, float* __restrict__ sind)
{
    int n = blockIdx.x, k = threadIdx.x;
    float p0 = pos[n * 3 + 0], p1 = pos[n * 3 + 1], p2 = pos[n * 3 + 2];
    float sd = sincn(0.1f * p0) * sincn(0.1f * p1) * sincn(0.1f * p2);
    if (k < NK) {
        float d = p0 * kgrid[k * 3 + 0] + p1 * kgrid[k * 3 + 1] + p2 * kgrid[k * 3 + 2];
        float sn, cs;
        sincosf(d, &sn, &cs);
        cosd[(size_t)n * NKP + k] = sd * cs;
        sind[(size_t)n * NKP + k] = sd * sn;
    } else {
        cosd[(size_t)n * NKP + k] = 0.f;
        sind[(size_t)n * NKP + k] = 0.f;
    }
}

__global__ __launch_bounds__(1024) void k_kdown(
    const float* __restrict__ krbf, const float* __restrict__ Wdown, float* __restrict__ kdown)
{
    int t = threadIdx.x;
    if (t < NK * 8) {
        int k = t >> 3, j = t & 7;
        float s = 0.f;
        for (int r = 0; r < 128; r++) s += krbf[k * 128 + r] * Wdown[r * 8 + j];
        kdown[t] = s;
    }
}

__global__ __launch_bounds__(256) void k_edge_geom(
    const float* __restrict__ pos, const float* __restrict__ shifts,
    const int* __restrict__ eidx, float* __restrict__ Y, float* __restrict__ ef)
{
    int e = blockIdx.x * 256 + threadIdx.x;
    if (e >= NE) return;
    int s = eidx[e], d = eidx[NE + e];
    float vx = pos[d * 3 + 0] - pos[s * 3 + 0] + shifts[e * 3 + 0];
    float vy = pos[d * 3 + 1] - pos[s * 3 + 1] + shifts[e * 3 + 1];
    float vz = pos[d * 3 + 2] - pos[s * 3 + 2] + shifts[e * 3 + 2];
    float r = sqrtf(vx * vx + vy * vy + vz * vz);
    float rinv = 1.0f / fmaxf(r, 1e-9f);
    float x = vx * rinv, y = vy * rinv, z = vz * rinv;

    const float s3 = 1.7320508075688772f, s5 = 2.2360679774997896f, s15 = 3.8729833462074170f;
    const float c70 = 2.0916500663351889f;   // sqrt(70)/4
    const float c105 = 10.246950765959598f;  // sqrt(105)
    const float c42 = 1.6201851746019651f;   // sqrt(42)/4
    const float c7 = 1.3228756555322954f;    // sqrt(7)/2
    float o[16];
    o[0] = 1.0f;
    o[1] = s3 * x; o[2] = s3 * y; o[3] = s3 * z;
    o[4] = s15 * x * y; o[5] = s15 * y * z; o[6] = 0.5f * s5 * (3.f * z * z - 1.f);
    o[7] = s15 * x * z; o[8] = 0.5f * s15 * (x * x - y * y);
    o[9]  = c70 * y * (3.f * x * x - y * y);
    o[10] = c105 * x * y * z;
    o[11] = c42 * y * (5.f * z * z - 1.f);
    o[12] = c7 * z * (5.f * z * z - 3.f);
    o[13] = c42 * x * (5.f * z * z - 1.f);
    o[14] = 0.5f * c105 * z * (x * x - y * y);
    o[15] = c70 * x * (x * x - 3.f * y * y);
    float4* Y4 = (float4*)(Y + (size_t)e * 16);
    Y4[0] = make_float4(o[0], o[1], o[2], o[3]);
    Y4[1] = make_float4(o[4], o[5], o[6], o[7]);
    Y4[2] = make_float4(o[8], o[9], o[10], o[11]);
    Y4[3] = make_float4(o[12], o[13], o[14], o[15]);

    float uu = fminf(fmaxf(r * 0.2f, 0.f), 1.f);
    float u2 = uu * uu, u4 = u2 * u2, u5 = u4 * uu, u6 = u5 * uu, u7 = u6 * uu;
    float env = 1.f - 21.f * u5 + 35.f * u6 - 15.f * u7;
    env = (r < 5.0f) ? env : 0.0f;
    float pref = 0.63245553203367587f * rinv * env;  // sqrt(2/5)/r * env
    const float pio5 = 0.62831853071795865f;         // pi/5
    float efv[8];
#pragma unroll
    for (int n1 = 1; n1 <= 8; n1++) efv[n1 - 1] = pref * sinf(n1 * pio5 * r);
    float4* E4 = (float4*)(ef + (size_t)e * 8);
    E4[0] = make_float4(efv[0], efv[1], efv[2], efv[3]);
    E4[1] = make_float4(efv[4], efv[5], efv[6], efv[7]);
}

// ---------------- CSR by dst ----------------
__global__ __launch_bounds__(256) void k_count(const int* __restrict__ eidx, int* __restrict__ deg)
{
    int e = blockIdx.x * 256 + threadIdx.x;
    if (e < NE) atomicAdd(&deg[eidx[NE + e]], 1);
}

__global__ __launch_bounds__(1024) void k_scan(
    const int* __restrict__ deg, int* __restrict__ offs, int* __restrict__ cursor)
{
    __shared__ int sc[1024];
    int tid = threadIdx.x;
    int base = tid * 4;
    int v[4]; int s = 0;
#pragma unroll
    for (int i = 0; i < 4; i++) {
        int idx = base + i;
        int d = (idx < NA) ? deg[idx] : 0;
        v[i] = s; s += d;
    }
    sc[tid] = s;
    __syncthreads();
    for (int ofs = 1; ofs < 1024; ofs <<= 1) {
        int t = (tid >= ofs) ? sc[tid - ofs] : 0;
        __syncthreads();
        sc[tid] += t;
        __syncthreads();
    }
    int excl = (tid > 0) ? sc[tid - 1] : 0;
#pragma unroll
    for (int i = 0; i < 4; i++) {
        int idx = base + i;
        if (idx < NA) { int o = excl + v[i]; offs[idx] = o; cursor[idx] = o; }
    }
    if (tid == 1023) offs[NA] = sc[1023];
}

__global__ __launch_bounds__(256) void k_fill(
    const int* __restrict__ eidx, int* __restrict__ cursor, int* __restrict__ perm)
{
    int e = blockIdx.x * 256 + threadIdx.x;
    if (e < NE) {
        int d = eidx[NE + e];
        int p = atomicAdd(&cursor[d], 1);
        perm[p] = e;
    }
}

// ---------------- Ewald kernels ----------------
__global__ __launch_bounds__(128) void k_kfilter(
    const float* __restrict__ kdown, const float* __restrict__ WupE, float* __restrict__ kf)
{
    int k = blockIdx.x, c = threadIdx.x;
    float s = 0.f;
#pragma unroll
    for (int j = 0; j < 8; j++) s += kdown[k * 8 + j] * WupE[j * C + c];
    kf[(size_t)k * C + c] = s;
}

// structure factors with filter fused: sfr = 0.01*kf * sum_n hres*cosd
__global__ __launch_bounds__(128) void k_sf(
    const float* __restrict__ hres, const float* __restrict__ cosd, const float* __restrict__ sind,
    const int* __restrict__ gs, const float* __restrict__ kf,
    float* __restrict__ sfr, float* __restrict__ sfi)
{
    int bk = blockIdx.x;
    int b = bk / NK, k = bk - b * NK;
    int c = threadIdx.x;
    int n0 = gs[b], n1 = gs[b + 1];
    float ar = 0.f, ai = 0.f;
    for (int n = n0; n < n1; n++) {
        float hc = hres[(size_t)n * C + c];
        float cd = cosd[(size_t)n * NKP + k];
        float sd = sind[(size_t)n * NKP + k];
        ar += hc * cd;
        ai += hc * sd;
    }
    float v = kf[(size_t)k * C + c] * 0.01f;
    sfr[(size_t)bk * C + c] = ar * v;
    sfi[(size_t)bk * C + c] = ai * v;
}

__global__ __launch_bounds__(128) void k_he(
    const float* __restrict__ cosd, const float* __restrict__ sind,
    const float* __restrict__ sfr, const float* __restrict__ sfi,
    const int* __restrict__ batch, float* __restrict__ out)
{
    int n = blockIdx.x, c = threadIdx.x;
    int b = batch[n];
    const float* pr = sfr + (size_t)b * NK * C;
    const float* pi = sfi + (size_t)b * NK * C;
    const float* cdp = cosd + (size_t)n * NKP;
    const float* sdp = sind + (size_t)n * NKP;
    float acc = 0.f;
    for (int k = 0; k < NK; k++) {
        acc += cdp[k] * pr[(size_t)k * C + c] + sdp[k] * pi[(size_t)k * C + c];
    }
    out[(size_t)n * C + c] = acc;
}

// ---------------- message gather + symmetric contraction ----------------
__global__ __launch_bounds__(128) void k_gather(
    const unsigned short* __restrict__ wbuf, const float* __restrict__ hu,
    const float* __restrict__ Y, const int* __restrict__ srcArr,
    const int* __restrict__ offs, const int* __restrict__ perm,
    const float* __restrict__ w2, const float* __restrict__ w3,
    float* __restrict__ feats)
{
    int n = blockIdx.x, c = threadIdx.x;
    int j0 = offs[n], j1 = offs[n + 1];
    float A[16];
#pragma unroll
    for (int s = 0; s < 16; s++) A[s] = 0.f;
    for (int j = j0; j < j1; j++) {
        int e = perm[j];
        int s = srcArr[e];
        float huc = hu[(size_t)s * C + c];
        ushort4 wv = *(const ushort4*)(wbuf + (size_t)e * 512 + c * 4);
        const float4* Yp = (const float4*)(Y + (size_t)e * 16);
        float4 y0 = Yp[0], y1 = Yp[1], y2 = Yp[2], y3 = Yp[3];
        float m0 = bf2f(wv.x) * huc, m1 = bf2f(wv.y) * huc;
        float m2 = bf2f(wv.z) * huc, m3 = bf2f(wv.w) * huc;
        A[0] += m0 * y0.x;
        A[1] += m1 * y0.y;  A[2]  += m1 * y0.z;  A[3]  += m1 * y0.w;
        A[4] += m2 * y1.x;  A[5]  += m2 * y1.y;  A[6]  += m2 * y1.z;  A[7] += m2 * y1.w;
        A[8] += m2 * y2.x;
        A[9] += m3 * y2.y;  A[10] += m3 * y2.z;  A[11] += m3 * y2.w;
        A[12] += m3 * y3.x; A[13] += m3 * y3.y;  A[14] += m3 * y3.z;  A[15] += m3 * y3.w;
    }
    const float inv = 1.0f / AVGN;
#pragma unroll
    for (int s = 0; s < 16; s++) A[s] *= inv;
    float scal = A[0];
    float i0 = A[0] * A[0];
    float i1 = A[1] * A[1] + A[2] * A[2] + A[3] * A[3];
    float i2 = A[4] * A[4] + A[5] * A[5] + A[6] * A[6] + A[7] * A[7] + A[8] * A[8];
    float i3 = A[9] * A[9] + A[10] * A[10] + A[11] * A[11] + A[12] * A[12] +
               A[13] * A[13] + A[14] * A[14] + A[15] * A[15];
    float t2 = i0 * w2[c] + i1 * w2[C + c] + i2 * w2[2 * C + c] + i3 * w2[3 * C + c];
    float t3 = i0 * w3[c] + i1 * w3[C + c] + i2 * w3[2 * C + c] + i3 * w3[3 * C + c];
    feats[(size_t)n * C + c] = scal + t2 + scal * t3;
}

// ---------------- readout energy ----------------
__global__ __launch_bounds__(128) void k_node_energy(
    const float* __restrict__ h, const int* __restrict__ batch,
    const float* __restrict__ Wr0, const float* __restrict__ Wr1a,
    const float* __restrict__ Wr1b, int mode, float* __restrict__ Eout)
{
    int n = blockIdx.x, t = threadIdx.x;
    __shared__ float hs[128];
    __shared__ float red[16];
    float hv = h[(size_t)n * C + t];
    if (mode == 0) {
        float v = hv * Wr0[t];
#pragma unroll
        for (int o = 32; o; o >>= 1) v += __shfl_down(v, o, 64);
        if ((t & 63) == 0) red[t >> 6] = v;
        __syncthreads();
        if (t == 0) atomicAdd(&Eout[batch[n]], red[0] + red[1]);
    } else {
        hs[t] = hv;
        __syncthreads();
        if (t < 16) {
            float s = 0.f;
#pragma unroll 8
            for (int cc = 0; cc < 128; cc++) s += hs[cc] * Wr1a[cc * 16 + t];
            red[t] = dsilu(s) * Wr1b[t];
        }
        __syncthreads();
        if (t == 0) {
            float s = 0.f;
#pragma unroll
            for (int j = 0; j < 16; j++) s += red[j];
            atomicAdd(&Eout[batch[n]], s);
        }
    }
}

// ---------------- workspace layout (floats) ----------------
constexpr size_t NAC   = (size_t)NA * C;       // 409600
constexpr size_t F_COSD = 0;
constexpr size_t F_SIND = F_COSD + (size_t)NA * NKP;
constexpr size_t F_Y    = F_SIND + (size_t)NA * NKP;
constexpr size_t F_EF   = F_Y + (size_t)NE * 16;
constexpr size_t F_H    = F_EF + (size_t)NE * 8;
constexpr size_t F_HN   = F_H + NAC;
constexpr size_t F_HRES = F_HN + NAC;
constexpr size_t F_T1   = F_HRES + NAC;
constexpr size_t F_T2   = F_T1 + NAC;
constexpr size_t F_HE2  = F_T2 + NAC;
constexpr size_t F_HU   = F_HE2 + NAC;
constexpr size_t F_FE   = F_HU + NAC;
constexpr size_t F_TA   = F_FE + NAC;
constexpr size_t F_TB   = F_TA + (size_t)NE * 64;
constexpr size_t F_W    = F_TB + (size_t)NE * 64;   // used as bf16 (NE*512 shorts)
constexpr size_t F_SFR  = F_W + (size_t)NE * 512;
constexpr size_t F_SFI  = F_SFR + (size_t)BG * NK * C;
constexpr size_t F_KD   = F_SFI + (size_t)BG * NK * C;
constexpr size_t F_KF   = F_KD + 1024;
constexpr size_t F_END  = F_KF + (size_t)NK * C;
constexpr size_t I_BASE = ((F_END * 4 + 255) / 256) * 256;  // byte offset of int region

extern "C" void kernel_launch(void* const* d_in, const int* in_sizes, int n_in,
                              void* d_out, int out_size, void* d_ws, size_t ws_size,
                              hipStream_t stream) {
    const float* pos    = (const float*)d_in[0];
    const float* na     = (const float*)d_in[1];
    const float* shifts = (const float*)d_in[2];
    const int*   eidx   = (const int*)d_in[3];
    const int*   batch  = (const int*)d_in[4];
    const float* kgrid  = (const float*)d_in[5];
    const float* krbf   = (const float*)d_in[6];
    const float* Wemb   = (const float*)d_in[7];
    const float* aE     = (const float*)d_in[8];
    const float* rW1    = (const float*)d_in[9];
    const float* rb1    = (const float*)d_in[10];
    const float* rW2    = (const float*)d_in[11];
    const float* rb2    = (const float*)d_in[12];
    const float* rW3    = (const float*)d_in[13];
    const float* rb3    = (const float*)d_in[14];
    const float* rW4    = (const float*)d_in[15];
    const float* Wup    = (const float*)d_in[16];
    const float* w2     = (const float*)d_in[17];
    const float* w3     = (const float*)d_in[18];
    const float* Wmix   = (const float*)d_in[19];
    const float* Wr0    = (const float*)d_in[20];
    const float* Wr1a   = (const float*)d_in[21];
    const float* Wr1b   = (const float*)d_in[22];
    const float* Wdown  = (const float*)d_in[23];
    const float* WupE   = (const float*)d_in[24];
    const float* Wpre1  = (const float*)d_in[25];
    const float* bpre1  = (const float*)d_in[26];
    const float* Wpre2  = (const float*)d_in[27];
    const float* bpre2  = (const float*)d_in[28];
    const float* Wm1    = (const float*)d_in[29];
    const float* bm1    = (const float*)d_in[30];
    const float* Wm2    = (const float*)d_in[31];
    const float* bm2    = (const float*)d_in[32];

    float* fw = (float*)d_ws;
    float* cosd = fw + F_COSD;
    float* sind = fw + F_SIND;
    float* Ybuf = fw + F_Y;
    float* efb  = fw + F_EF;
    float* h    = fw + F_H;
    float* hn   = fw + F_HN;
    float* hres = fw + F_HRES;
    float* t1   = fw + F_T1;
    float* t2   = fw + F_T2;
    float* he2  = fw + F_HE2;
    float* hu   = fw + F_HU;
    float* fe   = fw + F_FE;
    float* tA   = fw + F_TA;
    float* tB   = fw + F_TB;
    unsigned short* wbuf = (unsigned short*)(fw + F_W);
    float* sfr  = fw + F_SFR;
    float* sfi  = fw + F_SFI;
    float* kdwn = fw + F_KD;
    float* kfil = fw + F_KF;

    int* ip     = (int*)((char*)d_ws + I_BASE);
    int* deg    = ip;
    int* offs   = ip + NA;
    int* cursor = ip + 2 * NA + 1;
    int* perm   = ip + 3 * NA + 1;
    int* gs     = perm + NE;

    float* Eout = (float*)d_out;

    hipMemsetAsync(Eout, 0, BG * sizeof(float), stream);
    hipMemsetAsync(deg, 0, NA * sizeof(int), stream);

    k_node_init<<<NA, 128, 0, stream>>>(na, Wemb, aE, batch, h, Eout);
    k_ranges<<<1, 256, 0, stream>>>(batch, gs);
    k_kspace<<<NA, 128, 0, stream>>>(pos, kgrid, cosd, sind);
    k_kdown<<<1, 1024, 0, stream>>>(krbf, Wdown, kdwn);
    k_edge_geom<<<NE / 256, 256, 0, stream>>>(pos, shifts, eidx, Ybuf, efb);
    k_count<<<NE / 256, 256, 0, stream>>>(eidx, deg);
    k_scan<<<1, 1024, 0, stream>>>(deg, offs, cursor);
    k_fill<<<NE / 256, 256, 0, stream>>>(eidx, cursor, perm);

    const dim3 gA(NA / 64, C / 64);       // atom GEMMs: 50 x 2
    const dim3 gE1(NE / 64, 1);           // edge GEMMs N=64: 800 x 1
    const dim3 gE4(NE / 64, 512 / 64);    // edge GEMM N=512: 800 x 8

    for (int i = 0; i < 2; i++) {
        const float* Wpre1_i = Wpre1 + (size_t)i * C * C;
        const float* bpre1_i = bpre1 + (size_t)i * C;
        const float* Wpre2_i = Wpre2 + (size_t)i * C * C;
        const float* bpre2_i = bpre2 + (size_t)i * C;
        const float* WupE_i  = WupE + (size_t)i * 8 * C;
        const float* Wm1_i   = Wm1 + (size_t)i * C * C;
        const float* bm1_i   = bm1 + (size_t)i * C;
        const float* Wm2_i   = Wm2 + (size_t)i * C * C;
        const float* bm2_i   = bm2 + (size_t)i * C;
        const float* Wup_i   = Wup + (size_t)i * C * C;
        const float* rW1_i   = rW1 + (size_t)i * 8 * 64;
        const float* rb1_i   = rb1 + (size_t)i * 64;
        const float* rW2_i   = rW2 + (size_t)i * 64 * 64;
        const float* rb2_i   = rb2 + (size_t)i * 64;
        const float* rW3_i   = rW3 + (size_t)i * 64 * 64;
        const float* rb3_i   = rb3 + (size_t)i * 64;
        const float* rW4_i   = rW4 + (size_t)i * 64 * 512;
        const float* w2_i    = w2 + (size_t)i * 4 * C;
        const float* w3_i    = w3 + (size_t)i * 4 * C;
        const float* Wmix_i  = Wmix + (size_t)i * C * C;

        // Ewald branch
        gemm_kernel<128, 1, 0><<<gA, 256, 0, stream>>>(h, Wpre1_i, bpre1_i, nullptr, nullptr, t1, NA, C, 1.f);
        gemm_kernel<128, 0, 0><<<gA, 256, 0, stream>>>(t1, Wpre2_i, bpre2_i, h, nullptr, hres, NA, C, 1.f);
        k_kfilter<<<NK, 128, 0, stream>>>(kdwn, WupE_i, kfil);
        k_sf<<<BG * NK, 128, 0, stream>>>(hres, cosd, sind, gs, kfil, sfr, sfi);
        k_he<<<NA, 128, 0, stream>>>(cosd, sind, sfr, sfi, batch, t1);
        gemm_kernel<128, 1, 0><<<gA, 256, 0, stream>>>(t1, Wm1_i, bm1_i, nullptr, nullptr, t2, NA, C, 1.f);
        gemm_kernel<128, 1, 0><<<gA, 256, 0, stream>>>(t2, Wm2_i, bm2_i, nullptr, nullptr, he2, NA, C, 1.f);

        // message branch
        gemm_kernel<128, 0, 0><<<gA, 256, 0, stream>>>(h, Wup_i, nullptr, nullptr, nullptr, hu, NA, C, 1.f);
        gemm_kernel<8, 1, 0><<<gE1, 256, 0, stream>>>(efb, rW1_i, rb1_i, nullptr, nullptr, tA, NE, 64, 1.f);
        gemm_kernel<64, 1, 0><<<gE1, 256, 0, stream>>>(tA, rW2_i, rb2_i, nullptr, nullptr, tB, NE, 64, 1.f);
        gemm_kernel<64, 1, 0><<<gE1, 256, 0, stream>>>(tB, rW3_i, rb3_i, nullptr, nullptr, tA, NE, 64, 1.f);
        gemm_kernel<64, 0, 1><<<gE4, 256, 0, stream>>>(tA, rW4_i, nullptr, nullptr, nullptr, wbuf, NE, 512, 1.f);
        k_gather<<<NA, 128, 0, stream>>>(wbuf, hu, Ybuf, eidx, offs, perm, w2_i, w3_i, fe);

        // combine: h_new = SKIP * (feats@Wmix + h + he2)
        gemm_kernel<128, 0, 0><<<gA, 256, 0, stream>>>(fe, Wmix_i, nullptr, h, he2, hn, NA, C, SKIPF);
        k_node_energy<<<NA, 128, 0, stream>>>(hn, batch, Wr0, Wr1a, Wr1b, (i == 0) ? 0 : 1, Eout);

        float* tmp = h; h = hn; hn = tmp;
    }
}

// Round 3
// 756.515 us; speedup vs baseline: 1.7864x; 1.1928x over previous
//
#include <hip/hip_runtime.h>
#include <hip/hip_bf16.h>
#include <math.h>

// ---------------- problem constants ----------------
constexpr int NA  = 3200;     // atoms
constexpr int NE  = 51200;    // edges
constexpr int C   = 128;      // channels
constexpr int NK  = 123;      // k-points with |k| <= 0.6
constexpr int NKP = 128;      // padded stride for cosd/sind
constexpr int BG  = 8;        // graphs
constexpr float SKIPF = 0.57735026918962576f;  // 3^-0.5
constexpr float AVGN  = 16.0f;

__device__ __forceinline__ float dsilu(float x) { return x / (1.0f + expf(-x)); }

__device__ __forceinline__ unsigned short f2bf(float f) {
    unsigned int u = __float_as_uint(f);
    unsigned int r = (u + 0x7fffu + ((u >> 16) & 1u)) >> 16;
    return (unsigned short)r;
}
__device__ __forceinline__ float bf2f(unsigned short s) {
    return __uint_as_float(((unsigned int)s) << 16);
}

// ---------------- generic tiled f32 GEMM ----------------
template <int K, int ACT, int OBF16>
__global__ __launch_bounds__(256, 4) void gemm_kernel(
    const float* __restrict__ X, const float* __restrict__ W,
    const float* __restrict__ bias, const float* __restrict__ res1,
    const float* __restrict__ res2, void* __restrict__ outv,
    int M, int N, float scale)
{
    constexpr int K4 = K / 4;
    constexpr int BK  = (K < 64) ? K : 64;
    constexpr int BK4 = BK / 4;
    constexpr int BK4P = BK4 + 1;          // padded row stride (float4)
    __shared__ float As[64 * BK4P * 4];
    __shared__ float Bs[BK * 64];
    const int tid = threadIdx.x;
    const int m0 = blockIdx.x * 64;
    const int n0 = blockIdx.y * 64;

    const float4* X4 = (const float4*)X;
    const float4* W4 = (const float4*)W;
    float4* As4 = (float4*)As;
    float4* Bs4 = (float4*)Bs;
    const int N4 = N >> 2;

    const int tx = tid & 15;        // 4-col group
    const int ty = tid >> 4;        // 4-row group
    float acc[4][4];
#pragma unroll
    for (int i = 0; i < 4; i++)
#pragma unroll
        for (int j = 0; j < 4; j++) acc[i][j] = 0.0f;

    for (int k0 = 0; k0 < K4; k0 += BK4) {
        if (k0) __syncthreads();
        for (int idx = tid; idx < 64 * BK4; idx += 256) {
            int r = idx / BK4, k4 = idx - r * BK4;
            As4[r * BK4P + k4] = X4[(size_t)(m0 + r) * K4 + k0 + k4];
        }
        for (int idx = tid; idx < BK * 16; idx += 256) {
            int kr = idx >> 4, c4 = idx & 15;
            Bs4[idx] = W4[(size_t)(k0 * 4 + kr) * N4 + (n0 >> 2) + c4];
        }
        __syncthreads();

#pragma unroll 4
        for (int k4 = 0; k4 < BK4; k4++) {
            float a[4][4];
#pragma unroll
            for (int i = 0; i < 4; i++) {
                float4 av = As4[(ty * 4 + i) * BK4P + k4];
                a[i][0] = av.x; a[i][1] = av.y; a[i][2] = av.z; a[i][3] = av.w;
            }
#pragma unroll
            for (int kk = 0; kk < 4; kk++) {
                float4 bv = Bs4[(k4 * 4 + kk) * 16 + tx];
#pragma unroll
                for (int i = 0; i < 4; i++) {
                    acc[i][0] += a[i][kk] * bv.x;
                    acc[i][1] += a[i][kk] * bv.y;
                    acc[i][2] += a[i][kk] * bv.z;
                    acc[i][3] += a[i][kk] * bv.w;
                }
            }
        }
    }

    float4 bv = make_float4(0.f, 0.f, 0.f, 0.f);
    if (bias) bv = ((const float4*)bias)[(n0 >> 2) + tx];
#pragma unroll
    for (int i = 0; i < 4; i++) {
        int row = m0 + ty * 4 + i;
        size_t o = (size_t)row * N + n0 + tx * 4;
        float4 v;
        v.x = acc[i][0] + bv.x; v.y = acc[i][1] + bv.y;
        v.z = acc[i][2] + bv.z; v.w = acc[i][3] + bv.w;
        if (ACT) { v.x = dsilu(v.x); v.y = dsilu(v.y); v.z = dsilu(v.z); v.w = dsilu(v.w); }
        if (res1) { float4 r = *(const float4*)(res1 + o); v.x += r.x; v.y += r.y; v.z += r.z; v.w += r.w; }
        if (res2) { float4 r = *(const float4*)(res2 + o); v.x += r.x; v.y += r.y; v.z += r.z; v.w += r.w; }
        v.x *= scale; v.y *= scale; v.z *= scale; v.w *= scale;
        if (OBF16) {
            ushort4 pk;
            pk.x = f2bf(v.x); pk.y = f2bf(v.y); pk.z = f2bf(v.z); pk.w = f2bf(v.w);
            *(ushort4*)((unsigned short*)outv + o) = pk;
        } else {
            *(float4*)((float*)outv + o) = v;
        }
    }
}

// ---------------- setup kernels ----------------
__global__ __launch_bounds__(128) void k_node_init(
    const float* __restrict__ na, const float* __restrict__ Wemb,
    const float* __restrict__ aE, const int* __restrict__ batch,
    float* __restrict__ h, float* __restrict__ Eout)
{
    int n = blockIdx.x, c = threadIdx.x;
    float s = 0.f;
#pragma unroll
    for (int k = 0; k < 10; k++) s += na[n * 10 + k] * Wemb[k * C + c];
    h[(size_t)n * C + c] = s;
    if (c == 0) {
        float e = 0.f;
#pragma unroll
        for (int k = 0; k < 10; k++) e += na[n * 10 + k] * aE[k];
        atomicAdd(&Eout[batch[n]], e);
    }
}

__global__ __launch_bounds__(256) void k_ranges(const int* __restrict__ batch, int* __restrict__ gs)
{
    __shared__ int cnt[BG];
    if (threadIdx.x < BG) cnt[threadIdx.x] = 0;
    __syncthreads();
    for (int n = threadIdx.x; n < NA; n += 256) atomicAdd(&cnt[batch[n]], 1);
    __syncthreads();
    if (threadIdx.x == 0) {
        int s = 0;
        for (int b = 0; b < BG; b++) { gs[b] = s; s += cnt[b]; }
        gs[BG] = s;
    }
}

__device__ __forceinline__ float sincn(float x) {
    float px = 3.14159265358979323846f * x;
    return (fabsf(px) < 1e-8f) ? 1.0f : (sinf(px) / px);
}

__global__ __launch_bounds__(128) void k_kspace(
    const float* __restrict__ pos, const float* __restrict__ kgrid,
    float* __restrict__ cosd, float* __restrict__ sind)
{
    int n = blockIdx.x, k = threadIdx.x;
    float p0 = pos[n * 3 + 0], p1 = pos[n * 3 + 1], p2 = pos[n * 3 + 2];
    float sd = sincn(0.1f * p0) * sincn(0.1f * p1) * sincn(0.1f * p2);
    if (k < NK) {
        float d = p0 * kgrid[k * 3 + 0] + p1 * kgrid[k * 3 + 1] + p2 * kgrid[k * 3 + 2];
        float sn, cs;
        sincosf(d, &sn, &cs);
        cosd[(size_t)n * NKP + k] = sd * cs;
        sind[(size_t)n * NKP + k] = sd * sn;
    } else {
        cosd[(size_t)n * NKP + k] = 0.f;
        sind[(size_t)n * NKP + k] = 0.f;
    }
}

__global__ __launch_bounds__(1024) void k_kdown(
    const float* __restrict__ krbf, const float* __restrict__ Wdown, float* __restrict__ kdown)
{
    int t = threadIdx.x;
    if (t < NK * 8) {
        int k = t >> 3, j = t & 7;
        float s = 0.f;
        for (int r = 0; r < 128; r++) s += krbf[k * 128 + r] * Wdown[r * 8 + j];
        kdown[t] = s;
    }
}

__global__ __launch_bounds__(256) void k_edge_geom(
    const float* __restrict__ pos, const float* __restrict__ shifts,
    const int* __restrict__ eidx, float* __restrict__ Y, float* __restrict__ ef)
{
    int e = blockIdx.x * 256 + threadIdx.x;
    if (e >= NE) return;
    int s = eidx[e], d = eidx[NE + e];
    float vx = pos[d * 3 + 0] - pos[s * 3 + 0] + shifts[e * 3 + 0];
    float vy = pos[d * 3 + 1] - pos[s * 3 + 1] + shifts[e * 3 + 1];
    float vz = pos[d * 3 + 2] - pos[s * 3 + 2] + shifts[e * 3 + 2];
    float r = sqrtf(vx * vx + vy * vy + vz * vz);
    float rinv = 1.0f / fmaxf(r, 1e-9f);
    float x = vx * rinv, y = vy * rinv, z = vz * rinv;

    const float s3 = 1.7320508075688772f, s5 = 2.2360679774997896f, s15 = 3.8729833462074170f;
    const float c70 = 2.0916500663351889f;   // sqrt(70)/4
    const float c105 = 10.246950765959598f;  // sqrt(105)
    const float c42 = 1.6201851746019651f;   // sqrt(42)/4
    const float c7 = 1.3228756555322954f;    // sqrt(7)/2
    float o[16];
    o[0] = 1.0f;
    o[1] = s3 * x; o[2] = s3 * y; o[3] = s3 * z;
    o[4] = s15 * x * y; o[5] = s15 * y * z; o[6] = 0.5f * s5 * (3.f * z * z - 1.f);
    o[7] = s15 * x * z; o[8] = 0.5f * s15 * (x * x - y * y);
    o[9]  = c70 * y * (3.f * x * x - y * y);
    o[10] = c105 * x * y * z;
    o[11] = c42 * y * (5.f * z * z - 1.f);
    o[12] = c7 * z * (5.f * z * z - 3.f);
    o[13] = c42 * x * (5.f * z * z - 1.f);
    o[14] = 0.5f * c105 * z * (x * x - y * y);
    o[15] = c70 * x * (x * x - 3.f * y * y);
    float4* Y4 = (float4*)(Y + (size_t)e * 16);
    Y4[0] = make_float4(o[0], o[1], o[2], o[3]);
    Y4[1] = make_float4(o[4], o[5], o[6], o[7]);
    Y4[2] = make_float4(o[8], o[9], o[10], o[11]);
    Y4[3] = make_float4(o[12], o[13], o[14], o[15]);

    float uu = fminf(fmaxf(r * 0.2f, 0.f), 1.f);
    float u2 = uu * uu, u4 = u2 * u2, u5 = u4 * uu, u6 = u5 * uu, u7 = u6 * uu;
    float env = 1.f - 21.f * u5 + 35.f * u6 - 15.f * u7;
    env = (r < 5.0f) ? env : 0.0f;
    float pref = 0.63245553203367587f * rinv * env;  // sqrt(2/5)/r * env
    const float pio5 = 0.62831853071795865f;         // pi/5
    float efv[8];
#pragma unroll
    for (int n1 = 1; n1 <= 8; n1++) efv[n1 - 1] = pref * sinf(n1 * pio5 * r);
    float4* E4 = (float4*)(ef + (size_t)e * 8);
    E4[0] = make_float4(efv[0], efv[1], efv[2], efv[3]);
    E4[1] = make_float4(efv[4], efv[5], efv[6], efv[7]);
}

// ---------------- CSR by dst ----------------
__global__ __launch_bounds__(256) void k_count(const int* __restrict__ eidx, int* __restrict__ deg)
{
    int e = blockIdx.x * 256 + threadIdx.x;
    if (e < NE) atomicAdd(&deg[eidx[NE + e]], 1);
}

__global__ __launch_bounds__(1024) void k_scan(
    const int* __restrict__ deg, int* __restrict__ offs, int* __restrict__ cursor)
{
    __shared__ int sc[1024];
    int tid = threadIdx.x;
    int base = tid * 4;
    int v[4]; int s = 0;
#pragma unroll
    for (int i = 0; i < 4; i++) {
        int idx = base + i;
        int d = (idx < NA) ? deg[idx] : 0;
        v[i] = s; s += d;
    }
    sc[tid] = s;
    __syncthreads();
    for (int ofs = 1; ofs < 1024; ofs <<= 1) {
        int t = (tid >= ofs) ? sc[tid - ofs] : 0;
        __syncthreads();
        sc[tid] += t;
        __syncthreads();
    }
    int excl = (tid > 0) ? sc[tid - 1] : 0;
#pragma unroll
    for (int i = 0; i < 4; i++) {
        int idx = base + i;
        if (idx < NA) { int o = excl + v[i]; offs[idx] = o; cursor[idx] = o; }
    }
    if (tid == 1023) offs[NA] = sc[1023];
}

__global__ __launch_bounds__(256) void k_fill(
    const int* __restrict__ eidx, int* __restrict__ cursor, int* __restrict__ perm)
{
    int e = blockIdx.x * 256 + threadIdx.x;
    if (e < NE) {
        int d = eidx[NE + e];
        int p = atomicAdd(&cursor[d], 1);
        perm[p] = e;
    }
}

// ---------------- Ewald kernels ----------------
__global__ __launch_bounds__(128) void k_kfilter(
    const float* __restrict__ kdown, const float* __restrict__ WupE, float* __restrict__ kf)
{
    int k = blockIdx.x, c = threadIdx.x;
    float s = 0.f;
#pragma unroll
    for (int j = 0; j < 8; j++) s += kdown[k * 8 + j] * WupE[j * C + c];
    kf[(size_t)k * C + c] = s;
}

// Batched-GEMM structure factors, fused filter:
// sfr[b,k,c] += 0.01*kf[k,c] * sum_{n in chunk} hres[n,c]*cosd[n,k]  (likewise sfi/sind)
// grid = (BG, 4 k-tiles of 32, SPLIT n-chunks); block = 256.
// cosd/sind are zero-padded for k in [NK,128) so no k-guard needed in the MAC loop.
__global__ __launch_bounds__(256, 4) void k_sf(
    const float* __restrict__ hres, const float* __restrict__ cosd, const float* __restrict__ sind,
    const int* __restrict__ gs, const float* __restrict__ kf,
    float* __restrict__ sfr, float* __restrict__ sfi)
{
    constexpr int SPLIT = 8;
    const int b = blockIdx.x, kt = blockIdx.y, sp = blockIdx.z;
    const int n0 = gs[b], n1 = gs[b + 1];
    const int cnt = n1 - n0;
    const int per = (cnt + SPLIT - 1) / SPLIT;
    const int cs = n0 + sp * per;
    const int ce = min(cs + per, n1);

    __shared__ float Hs[32 * 128];   // 16 KB
    __shared__ float Cs[32 * 32];    // 4 KB
    __shared__ float Ss[32 * 32];    // 4 KB

    const int tid = threadIdx.x;
    const int tx = tid & 31;   // c-group: 4 channels each
    const int ty = tid >> 5;   // k-group: 4 k each (8 groups * 4 = 32 k)

    float accR[4][4], accI[4][4];
#pragma unroll
    for (int i = 0; i < 4; i++)
#pragma unroll
        for (int j = 0; j < 4; j++) { accR[i][j] = 0.f; accI[i][j] = 0.f; }

    float4* H4 = (float4*)Hs;
    float4* C4 = (float4*)Cs;
    float4* S4 = (float4*)Ss;

    for (int nb = cs; nb < ce; nb += 32) {
        __syncthreads();
        // stage hres rows (32 x 128 f32)
        for (int idx = tid; idx < 32 * 32; idx += 256) {
            int r = idx >> 5, c4 = idx & 31;
            int n = nb + r;
            H4[idx] = (n < ce) ? ((const float4*)hres)[(size_t)n * 32 + c4]
                               : make_float4(0.f, 0.f, 0.f, 0.f);
        }
        // stage cosd/sind tiles (32 x 32 f32)
        for (int idx = tid; idx < 32 * 8; idx += 256) {
            int r = idx >> 3, k4 = idx & 7;
            int n = nb + r;
            float4 cv = make_float4(0.f, 0.f, 0.f, 0.f), sv = cv;
            if (n < ce) {
                cv = ((const float4*)cosd)[(size_t)n * 32 + kt * 8 + k4];
                sv = ((const float4*)sind)[(size_t)n * 32 + kt * 8 + k4];
            }
            C4[idx] = cv;
            S4[idx] = sv;
        }
        __syncthreads();
        const int lim = min(32, ce - nb);
        for (int n = 0; n < lim; n++) {
            float4 hv = H4[n * 32 + tx];
            float4 cv = C4[n * 8 + ty];
            float4 sv = S4[n * 8 + ty];
            float h[4] = { hv.x, hv.y, hv.z, hv.w };
            float ck[4] = { cv.x, cv.y, cv.z, cv.w };
            float sk[4] = { sv.x, sv.y, sv.z, sv.w };
#pragma unroll
            for (int i = 0; i < 4; i++)
#pragma unroll
                for (int j = 0; j < 4; j++) {
                    accR[i][j] += ck[i] * h[j];
                    accI[i][j] += sk[i] * h[j];
                }
        }
    }

    const int kbase = kt * 32 + ty * 4;
#pragma unroll
    for (int i = 0; i < 4; i++) {
        int k = kbase + i;
        if (k < NK) {
            float4 kfv = ((const float4*)kf)[(size_t)k * 32 + tx];
            float vx = kfv.x * 0.01f, vy = kfv.y * 0.01f, vz = kfv.z * 0.01f, vw = kfv.w * 0.01f;
            float* pR = sfr + ((size_t)(b * NK + k)) * C + tx * 4;
            float* pI = sfi + ((size_t)(b * NK + k)) * C + tx * 4;
            atomicAdd(pR + 0, accR[i][0] * vx);
            atomicAdd(pR + 1, accR[i][1] * vy);
            atomicAdd(pR + 2, accR[i][2] * vz);
            atomicAdd(pR + 3, accR[i][3] * vw);
            atomicAdd(pI + 0, accI[i][0] * vx);
            atomicAdd(pI + 1, accI[i][1] * vy);
            atomicAdd(pI + 2, accI[i][2] * vz);
            atomicAdd(pI + 3, accI[i][3] * vw);
        }
    }
}

__global__ __launch_bounds__(128) void k_he(
    const float* __restrict__ cosd, const float* __restrict__ sind,
    const float* __restrict__ sfr, const float* __restrict__ sfi,
    const int* __restrict__ batch, float* __restrict__ out)
{
    int n = blockIdx.x, c = threadIdx.x;
    int b = batch[n];
    const float* pr = sfr + (size_t)b * NK * C;
    const float* pi = sfi + (size_t)b * NK * C;
    const float* cdp = cosd + (size_t)n * NKP;
    const float* sdp = sind + (size_t)n * NKP;
    float acc = 0.f;
    for (int k = 0; k < NK; k++) {
        acc += cdp[k] * pr[(size_t)k * C + c] + sdp[k] * pi[(size_t)k * C + c];
    }
    out[(size_t)n * C + c] = acc;
}

// ---------------- message gather + symmetric contraction ----------------
__global__ __launch_bounds__(128) void k_gather(
    const unsigned short* __restrict__ wbuf, const float* __restrict__ hu,
    const float* __restrict__ Y, const int* __restrict__ srcArr,
    const int* __restrict__ offs, const int* __restrict__ perm,
    const float* __restrict__ w2, const float* __restrict__ w3,
    float* __restrict__ feats)
{
    int n = blockIdx.x, c = threadIdx.x;
    int j0 = offs[n], j1 = offs[n + 1];
    float A[16];
#pragma unroll
    for (int s = 0; s < 16; s++) A[s] = 0.f;
    for (int j = j0; j < j1; j++) {
        int e = perm[j];
        int s = srcArr[e];
        float huc = hu[(size_t)s * C + c];
        ushort4 wv = *(const ushort4*)(wbuf + (size_t)e * 512 + c * 4);
        const float4* Yp = (const float4*)(Y + (size_t)e * 16);
        float4 y0 = Yp[0], y1 = Yp[1], y2 = Yp[2], y3 = Yp[3];
        float m0 = bf2f(wv.x) * huc, m1 = bf2f(wv.y) * huc;
        float m2 = bf2f(wv.z) * huc, m3 = bf2f(wv.w) * huc;
        A[0] += m0 * y0.x;
        A[1] += m1 * y0.y;  A[2]  += m1 * y0.z;  A[3]  += m1 * y0.w;
        A[4] += m2 * y1.x;  A[5]  += m2 * y1.y;  A[6]  += m2 * y1.z;  A[7] += m2 * y1.w;
        A[8] += m2 * y2.x;
        A[9] += m3 * y2.y;  A[10] += m3 * y2.z;  A[11] += m3 * y2.w;
        A[12] += m3 * y3.x; A[13] += m3 * y3.y;  A[14] += m3 * y3.z;  A[15] += m3 * y3.w;
    }
    const float inv = 1.0f / AVGN;
#pragma unroll
    for (int s = 0; s < 16; s++) A[s] *= inv;
    float scal = A[0];
    float i0 = A[0] * A[0];
    float i1 = A[1] * A[1] + A[2] * A[2] + A[3] * A[3];
    float i2 = A[4] * A[4] + A[5] * A[5] + A[6] * A[6] + A[7] * A[7] + A[8] * A[8];
    float i3 = A[9] * A[9] + A[10] * A[10] + A[11] * A[11] + A[12] * A[12] +
               A[13] * A[13] + A[14] * A[14] + A[15] * A[15];
    float t2 = i0 * w2[c] + i1 * w2[C + c] + i2 * w2[2 * C + c] + i3 * w2[3 * C + c];
    float t3 = i0 * w3[c] + i1 * w3[C + c] + i2 * w3[2 * C + c] + i3 * w3[3 * C + c];
    feats[(size_t)n * C + c] = scal + t2 + scal * t3;
}

// ---------------- readout energy ----------------
__global__ __launch_bounds__(128) void k_node_energy(
    const float* __restrict__ h, const int* __restrict__ batch,
    const float* __restrict__ Wr0, const float* __restrict__ Wr1a,
    const float* __restrict__ Wr1b, int mode, float* __restrict__ Eout)
{
    int n = blockIdx.x, t = threadIdx.x;
    __shared__ float hs[128];
    __shared__ float red[16];
    float hv = h[(size_t)n * C + t];
    if (mode == 0) {
        float v = hv * Wr0[t];
#pragma unroll
        for (int o = 32; o; o >>= 1) v += __shfl_down(v, o, 64);
        if ((t & 63) == 0) red[t >> 6] = v;
        __syncthreads();
        if (t == 0) atomicAdd(&Eout[batch[n]], red[0] + red[1]);
    } else {
        hs[t] = hv;
        __syncthreads();
        if (t < 16) {
            float s = 0.f;
#pragma unroll 8
            for (int cc = 0; cc < 128; cc++) s += hs[cc] * Wr1a[cc * 16 + t];
            red[t] = dsilu(s) * Wr1b[t];
        }
        __syncthreads();
        if (t == 0) {
            float s = 0.f;
#pragma unroll
            for (int j = 0; j < 16; j++) s += red[j];
            atomicAdd(&Eout[batch[n]], s);
        }
    }
}

// ---------------- workspace layout (floats) ----------------
constexpr size_t NAC   = (size_t)NA * C;       // 409600
constexpr size_t F_COSD = 0;
constexpr size_t F_SIND = F_COSD + (size_t)NA * NKP;
constexpr size_t F_Y    = F_SIND + (size_t)NA * NKP;
constexpr size_t F_EF   = F_Y + (size_t)NE * 16;
constexpr size_t F_H    = F_EF + (size_t)NE * 8;
constexpr size_t F_HN   = F_H + NAC;
constexpr size_t F_HRES = F_HN + NAC;
constexpr size_t F_T1   = F_HRES + NAC;
constexpr size_t F_T2   = F_T1 + NAC;
constexpr size_t F_HE2  = F_T2 + NAC;
constexpr size_t F_HU   = F_HE2 + NAC;
constexpr size_t F_FE   = F_HU + NAC;
constexpr size_t F_TA   = F_FE + NAC;
constexpr size_t F_TB   = F_TA + (size_t)NE * 64;
constexpr size_t F_W    = F_TB + (size_t)NE * 64;   // used as bf16 (NE*512 shorts)
constexpr size_t F_SFR  = F_W + (size_t)NE * 512;
constexpr size_t F_SFI  = F_SFR + (size_t)BG * NK * C;
constexpr size_t F_KD   = F_SFI + (size_t)BG * NK * C;
constexpr size_t F_KF   = F_KD + 1024;
constexpr size_t F_END  = F_KF + (size_t)NK * C;
constexpr size_t I_BASE = ((F_END * 4 + 255) / 256) * 256;  // byte offset of int region

extern "C" void kernel_launch(void* const* d_in, const int* in_sizes, int n_in,
                              void* d_out, int out_size, void* d_ws, size_t ws_size,
                              hipStream_t stream) {
    const float* pos    = (const float*)d_in[0];
    const float* na     = (const float*)d_in[1];
    const float* shifts = (const float*)d_in[2];
    const int*   eidx   = (const int*)d_in[3];
    const int*   batch  = (const int*)d_in[4];
    const float* kgrid  = (const float*)d_in[5];
    const float* krbf   = (const float*)d_in[6];
    const float* Wemb   = (const float*)d_in[7];
    const float* aE     = (const float*)d_in[8];
    const float* rW1    = (const float*)d_in[9];
    const float* rb1    = (const float*)d_in[10];
    const float* rW2    = (const float*)d_in[11];
    const float* rb2    = (const float*)d_in[12];
    const float* rW3    = (const float*)d_in[13];
    const float* rb3    = (const float*)d_in[14];
    const float* rW4    = (const float*)d_in[15];
    const float* Wup    = (const float*)d_in[16];
    const float* w2     = (const float*)d_in[17];
    const float* w3     = (const float*)d_in[18];
    const float* Wmix   = (const float*)d_in[19];
    const float* Wr0    = (const float*)d_in[20];
    const float* Wr1a   = (const float*)d_in[21];
    const float* Wr1b   = (const float*)d_in[22];
    const float* Wdown  = (const float*)d_in[23];
    const float* WupE   = (const float*)d_in[24];
    const float* Wpre1  = (const float*)d_in[25];
    const float* bpre1  = (const float*)d_in[26];
    const float* Wpre2  = (const float*)d_in[27];
    const float* bpre2  = (const float*)d_in[28];
    const float* Wm1    = (const float*)d_in[29];
    const float* bm1    = (const float*)d_in[30];
    const float* Wm2    = (const float*)d_in[31];
    const float* bm2    = (const float*)d_in[32];

    float* fw = (float*)d_ws;
    float* cosd = fw + F_COSD;
    float* sind = fw + F_SIND;
    float* Ybuf = fw + F_Y;
    float* efb  = fw + F_EF;
    float* h    = fw + F_H;
    float* hn   = fw + F_HN;
    float* hres = fw + F_HRES;
    float* t1   = fw + F_T1;
    float* t2   = fw + F_T2;
    float* he2  = fw + F_HE2;
    float* hu   = fw + F_HU;
    float* fe   = fw + F_FE;
    float* tA   = fw + F_TA;
    float* tB   = fw + F_TB;
    unsigned short* wbuf = (unsigned short*)(fw + F_W);
    float* sfr  = fw + F_SFR;
    float* sfi  = fw + F_SFI;
    float* kdwn = fw + F_KD;
    float* kfil = fw + F_KF;

    int* ip     = (int*)((char*)d_ws + I_BASE);
    int* deg    = ip;
    int* offs   = ip + NA;
    int* cursor = ip + 2 * NA + 1;
    int* perm   = ip + 3 * NA + 1;
    int* gs     = perm + NE;

    float* Eout = (float*)d_out;

    hipMemsetAsync(Eout, 0, BG * sizeof(float), stream);
    hipMemsetAsync(deg, 0, NA * sizeof(int), stream);

    k_node_init<<<NA, 128, 0, stream>>>(na, Wemb, aE, batch, h, Eout);
    k_ranges<<<1, 256, 0, stream>>>(batch, gs);
    k_kspace<<<NA, 128, 0, stream>>>(pos, kgrid, cosd, sind);
    k_kdown<<<1, 1024, 0, stream>>>(krbf, Wdown, kdwn);
    k_edge_geom<<<NE / 256, 256, 0, stream>>>(pos, shifts, eidx, Ybuf, efb);
    k_count<<<NE / 256, 256, 0, stream>>>(eidx, deg);
    k_scan<<<1, 1024, 0, stream>>>(deg, offs, cursor);
    k_fill<<<NE / 256, 256, 0, stream>>>(eidx, cursor, perm);

    const dim3 gA(NA / 64, C / 64);       // atom GEMMs: 50 x 2
    const dim3 gE1(NE / 64, 1);           // edge GEMMs N=64: 800 x 1
    const dim3 gE4(NE / 64, 512 / 64);    // edge GEMM N=512: 800 x 8
    const dim3 gSF(BG, 4, 8);             // structure-factor GEMM

    for (int i = 0; i < 2; i++) {
        const float* Wpre1_i = Wpre1 + (size_t)i * C * C;
        const float* bpre1_i = bpre1 + (size_t)i * C;
        const float* Wpre2_i = Wpre2 + (size_t)i * C * C;
        const float* bpre2_i = bpre2 + (size_t)i * C;
        const float* WupE_i  = WupE + (size_t)i * 8 * C;
        const float* Wm1_i   = Wm1 + (size_t)i * C * C;
        const float* bm1_i   = bm1 + (size_t)i * C;
        const float* Wm2_i   = Wm2 + (size_t)i * C * C;
        const float* bm2_i   = bm2 + (size_t)i * C;
        const float* Wup_i   = Wup + (size_t)i * C * C;
        const float* rW1_i   = rW1 + (size_t)i * 8 * 64;
        const float* rb1_i   = rb1 + (size_t)i * 64;
        const float* rW2_i   = rW2 + (size_t)i * 64 * 64;
        const float* rb2_i   = rb2 + (size_t)i * 64;
        const float* rW3_i   = rW3 + (size_t)i * 64 * 64;
        const float* rb3_i   = rb3 + (size_t)i * 64;
        const float* rW4_i   = rW4 + (size_t)i * 64 * 512;
        const float* w2_i    = w2 + (size_t)i * 4 * C;
        const float* w3_i    = w3 + (size_t)i * 4 * C;
        const float* Wmix_i  = Wmix + (size_t)i * C * C;

        // Ewald branch
        gemm_kernel<128, 1, 0><<<gA, 256, 0, stream>>>(h, Wpre1_i, bpre1_i, nullptr, nullptr, t1, NA, C, 1.f);
        gemm_kernel<128, 0, 0><<<gA, 256, 0, stream>>>(t1, Wpre2_i, bpre2_i, h, nullptr, hres, NA, C, 1.f);
        k_kfilter<<<NK, 128, 0, stream>>>(kdwn, WupE_i, kfil);
        hipMemsetAsync(sfr, 0, 2 * (size_t)BG * NK * C * sizeof(float), stream);  // sfr+sfi contiguous
        k_sf<<<gSF, 256, 0, stream>>>(hres, cosd, sind, gs, kfil, sfr, sfi);
        k_he<<<NA, 128, 0, stream>>>(cosd, sind, sfr, sfi, batch, t1);
        gemm_kernel<128, 1, 0><<<gA, 256, 0, stream>>>(t1, Wm1_i, bm1_i, nullptr, nullptr, t2, NA, C, 1.f);
        gemm_kernel<128, 1, 0><<<gA, 256, 0, stream>>>(t2, Wm2_i, bm2_i, nullptr, nullptr, he2, NA, C, 1.f);

        // message branch
        gemm_kernel<128, 0, 0><<<gA, 256, 0, stream>>>(h, Wup_i, nullptr, nullptr, nullptr, hu, NA, C, 1.f);
        gemm_kernel<8, 1, 0><<<gE1, 256, 0, stream>>>(efb, rW1_i, rb1_i, nullptr, nullptr, tA, NE, 64, 1.f);
        gemm_kernel<64, 1, 0><<<gE1, 256, 0, stream>>>(tA, rW2_i, rb2_i, nullptr, nullptr, tB, NE, 64, 1.f);
        gemm_kernel<64, 1, 0><<<gE1, 256, 0, stream>>>(tB, rW3_i, rb3_i, nullptr, nullptr, tA, NE, 64, 1.f);
        gemm_kernel<64, 0, 1><<<gE4, 256, 0, stream>>>(tA, rW4_i, nullptr, nullptr, nullptr, wbuf, NE, 512, 1.f);
        k_gather<<<NA, 128, 0, stream>>>(wbuf, hu, Ybuf, eidx, offs, perm, w2_i, w3_i, fe);

        // combine: h_new = SKIP * (feats@Wmix + h + he2)
        gemm_kernel<128, 0, 0><<<gA, 256, 0, stream>>>(fe, Wmix_i, nullptr, h, he2, hn, NA, C, SKIPF);
        k_node_energy<<<NA, 128, 0, stream>>>(hn, batch, Wr0, Wr1a, Wr1b, (i == 0) ? 0 : 1, Eout);

        float* tmp = h; h = hn; hn = tmp;
    }
}